// Round 1
// baseline (2509.200 us; speedup 1.0000x reference)
//
#include <hip/hip_runtime.h>
#include <math.h>

// Problem constants (fixed by setup_inputs: b=2, H=W=T=24, c=512, heads=8)
constexpr int Cc     = 512;
constexpr int NHEAD  = 8;
constexpr int HD     = 64;
constexpr int NTOK   = 13824;          // tokens per batch element (24^3)
constexpr int BATCH  = 2;
constexpr int M_TOT  = BATCH * NTOK;   // 27648 total rows
constexpr int QKV_LD = 3 * Cc;         // 1536
constexpr int SEQLEN = 576;            // 24*24 per decomposed attention
constexpr int NTILE  = SEQLEN / 64;    // 9 k-tiles of 64

// ---------------------------------------------------------------------------
// fp32 tiled GEMM: C[M,N] = A[M,K] @ B[K,N], row-major.
// BM=BN=128, BK=8, 256 threads, 8x8 micro-tile per thread.
// Requires M%128==0, N%128==0, K%8==0 (true for all our shapes).
// ---------------------------------------------------------------------------
__global__ __launch_bounds__(256, 2)
void sgemm128(const float* __restrict__ A, const float* __restrict__ B,
              float* __restrict__ C, int M, int N, int K) {
  constexpr int BM = 128, BN = 128, BK = 8;
  __shared__ float As[BK][BM];   // transposed A tile
  __shared__ float Bs[BK][BN];

  const int nbx = N / BN;
  const int bx = blockIdx.x % nbx;
  const int by = blockIdx.x / nbx;
  const int tid = threadIdx.x;
  const int tx = tid & 15;        // 0..15 -> output col group
  const int ty = tid >> 4;        // 0..15 -> output row group

  float acc[8][8] = {};

  const float* Ab = A + (size_t)by * BM * K;
  const float* Bb = B + (size_t)bx * BN;

  const int ar = tid >> 1;             // 0..127 : A row within tile
  const int ac = (tid & 1) << 2;       // 0 or 4 : A col within BK
  const int br = tid >> 5;             // 0..7   : B row within BK
  const int bc = (tid & 31) << 2;      // 0..124 : B col within tile

  for (int k0 = 0; k0 < K; k0 += BK) {
    float4 av = *(const float4*)(Ab + (size_t)ar * K + k0 + ac);
    float4 bv = *(const float4*)(Bb + (size_t)(k0 + br) * N + bc);
    __syncthreads();  // previous iteration's reads complete before overwrite
    As[ac + 0][ar] = av.x;
    As[ac + 1][ar] = av.y;
    As[ac + 2][ar] = av.z;
    As[ac + 3][ar] = av.w;
    *(float4*)&Bs[br][bc] = bv;
    __syncthreads();

#pragma unroll
    for (int kk = 0; kk < BK; ++kk) {
      float a[8], b[8];
      *(float4*)(a)     = *(const float4*)&As[kk][ty * 8];
      *(float4*)(a + 4) = *(const float4*)&As[kk][ty * 8 + 4];
      *(float4*)(b)     = *(const float4*)&Bs[kk][tx * 8];
      *(float4*)(b + 4) = *(const float4*)&Bs[kk][tx * 8 + 4];
#pragma unroll
      for (int i = 0; i < 8; ++i) {
#pragma unroll
        for (int j = 0; j < 8; ++j) {
          acc[i][j] = fmaf(a[i], b[j], acc[i][j]);
        }
      }
    }
  }

  float* Cb = C + (size_t)(by * BM + ty * 8) * N + bx * BN + tx * 8;
#pragma unroll
  for (int i = 0; i < 8; ++i) {
    float4 c0 = make_float4(acc[i][0], acc[i][1], acc[i][2], acc[i][3]);
    float4 c1 = make_float4(acc[i][4], acc[i][5], acc[i][6], acc[i][7]);
    *(float4*)(Cb + (size_t)i * N)     = c0;
    *(float4*)(Cb + (size_t)i * N + 4) = c1;
  }
}

// ---------------------------------------------------------------------------
// Flash attention over one decomposition.
// seq s in [0,576): s1 = s/24, s2 = s%24; token n = s1*str1 + s2*str2 + e*strE
// grid: 48 (b*axis) * 8 (heads) * 9 (q tiles of 64) = 3456 blocks, 256 thr.
// Q/K/V/P tiles 64x64 fp32 in LDS (64 KiB), XOR chunk swizzle:
//   float index = row*64 + ((col/4 ^ (row/4 & 15)) * 4 + col%4)
// conflict-free ds_read_b128 for both row-gather (QK^T) and col-slice (PV).
// ---------------------------------------------------------------------------
__device__ __forceinline__ int swz(int row, int col) {
  int chunk = (col >> 2) ^ ((row >> 2) & 15);
  return row * 64 + (chunk << 2) + (col & 3);
}

__global__ __launch_bounds__(256, 2)
void attn_decomp(const float* __restrict__ qkv, float* __restrict__ osum,
                 int str1, int str2, int strE, int accumulate) {
  __shared__ float Qs[64 * 64];
  __shared__ float Ks[64 * 64];
  __shared__ float Vs[64 * 64];
  __shared__ float Ps[64 * 64];

  const int bi   = blockIdx.x;
  const int qt   = bi % NTILE;          // q tile 0..8
  const int head = (bi / NTILE) & 7;
  const int be   = bi / (NTILE * NHEAD);  // 0..47
  const int bb   = be / 24;             // batch
  const int e    = be % 24;             // extra (non-seq) axis value

  const int tid = threadIdx.x;
  const int tx  = tid & 15;   // key/out-dim group
  const int ty  = tid >> 4;   // query row group

  const size_t base_tok = (size_t)bb * NTOK + (size_t)e * strE;
  const float* qbase = qkv + base_tok * QKV_LD + head * HD;
  const float* kbase = qbase + Cc;
  const float* vbase = qbase + 2 * Cc;

  // ---- stage Q (scaled by sqrt(hd) = 8, per reference q*scale) ----
  {
    const int cc = tid & 15;   // 16B chunk within row
    const int r0 = tid >> 4;   // 0..15
#pragma unroll
    for (int p = 0; p < 4; ++p) {
      int r = p * 16 + r0;
      int s = qt * 64 + r;
      int n_off = (s / 24) * str1 + (s % 24) * str2;
      float4 v = *(const float4*)(qbase + (size_t)n_off * QKV_LD + cc * 4);
      v.x *= 8.0f; v.y *= 8.0f; v.z *= 8.0f; v.w *= 8.0f;
      *(float4*)&Qs[swz(r, cc * 4)] = v;
    }
  }

  float m_run[4], l_run[4], Oa[4][4];
#pragma unroll
  for (int i = 0; i < 4; ++i) {
    m_run[i] = -1e30f;
    l_run[i] = 0.0f;
#pragma unroll
    for (int j = 0; j < 4; ++j) Oa[i][j] = 0.0f;
  }

  for (int kt = 0; kt < NTILE; ++kt) {
    __syncthreads();  // previous PV reads of Ks/Vs complete
    // ---- stage K and V tiles ----
    {
      const int cc = tid & 15;
      const int r0 = tid >> 4;
#pragma unroll
      for (int p = 0; p < 4; ++p) {
        int r = p * 16 + r0;
        int s = kt * 64 + r;
        size_t n_off = (size_t)((s / 24) * str1 + (s % 24) * str2) * QKV_LD;
        float4 kv4 = *(const float4*)(kbase + n_off + cc * 4);
        float4 vv4 = *(const float4*)(vbase + n_off + cc * 4);
        *(float4*)&Ks[swz(r, cc * 4)] = kv4;
        *(float4*)&Vs[swz(r, cc * 4)] = vv4;
      }
    }
    __syncthreads();

    // ---- S = Q K^T : thread computes rows 4ty+i, cols 4tx+j ----
    float s_[4][4] = {};
#pragma unroll
    for (int dc = 0; dc < 16; ++dc) {
      float qv[4][4], kv[4][4];
#pragma unroll
      for (int i = 0; i < 4; ++i)
        *(float4*)qv[i] = *(const float4*)&Qs[swz(ty * 4 + i, dc * 4)];
#pragma unroll
      for (int j = 0; j < 4; ++j)
        *(float4*)kv[j] = *(const float4*)&Ks[swz(tx * 4 + j, dc * 4)];
#pragma unroll
      for (int i = 0; i < 4; ++i)
#pragma unroll
        for (int j = 0; j < 4; ++j)
#pragma unroll
          for (int d = 0; d < 4; ++d)
            s_[i][j] = fmaf(qv[i][d], kv[j][d], s_[i][j]);
    }

    // ---- online softmax update (row reduces across the 16 tx lanes) ----
    float tmax[4], tsum[4], alpha[4];
#pragma unroll
    for (int i = 0; i < 4; ++i) {
      tmax[i] = fmaxf(fmaxf(s_[i][0], s_[i][1]), fmaxf(s_[i][2], s_[i][3]));
#pragma unroll
      for (int off = 1; off < 16; off <<= 1)
        tmax[i] = fmaxf(tmax[i], __shfl_xor(tmax[i], off));
      float mn = fmaxf(m_run[i], tmax[i]);
      alpha[i] = __expf(m_run[i] - mn);
      m_run[i] = mn;
    }
#pragma unroll
    for (int i = 0; i < 4; ++i) {
#pragma unroll
      for (int j = 0; j < 4; ++j) s_[i][j] = __expf(s_[i][j] - m_run[i]);
      tsum[i] = s_[i][0] + s_[i][1] + s_[i][2] + s_[i][3];
#pragma unroll
      for (int off = 1; off < 16; off <<= 1)
        tsum[i] += __shfl_xor(tsum[i], off);
      l_run[i] = l_run[i] * alpha[i] + tsum[i];
#pragma unroll
      for (int j = 0; j < 4; ++j) Oa[i][j] *= alpha[i];
    }
    // ---- write P to LDS ----
#pragma unroll
    for (int i = 0; i < 4; ++i) {
      float4 p4 = make_float4(s_[i][0], s_[i][1], s_[i][2], s_[i][3]);
      *(float4*)&Ps[swz(ty * 4 + i, tx * 4)] = p4;
    }
    __syncthreads();

    // ---- O += P @ V : thread owns rows 4ty+i, out dims 4tx+j ----
#pragma unroll
    for (int kc = 0; kc < 16; ++kc) {
      float pv[4][4], vv[4][4];
#pragma unroll
      for (int i = 0; i < 4; ++i)
        *(float4*)pv[i] = *(const float4*)&Ps[swz(ty * 4 + i, kc * 4)];
#pragma unroll
      for (int kk = 0; kk < 4; ++kk)
        *(float4*)vv[kk] = *(const float4*)&Vs[swz(kc * 4 + kk, tx * 4)];
#pragma unroll
      for (int i = 0; i < 4; ++i)
#pragma unroll
        for (int j = 0; j < 4; ++j)
#pragma unroll
          for (int kk = 0; kk < 4; ++kk)
            Oa[i][j] = fmaf(pv[i][kk], vv[kk][j], Oa[i][j]);
    }
  }

  // ---- epilogue: normalize and write/accumulate ----
#pragma unroll
  for (int i = 0; i < 4; ++i) {
    float inv = 1.0f / l_run[i];
    int s = qt * 64 + ty * 4 + i;
    size_t row = base_tok + (size_t)((s / 24) * str1 + (s % 24) * str2);
    float* op = osum + row * Cc + head * HD + tx * 4;
    float4 o4 = make_float4(Oa[i][0] * inv, Oa[i][1] * inv,
                            Oa[i][2] * inv, Oa[i][3] * inv);
    if (accumulate) {
      float4 prev = *(const float4*)op;
      o4.x += prev.x; o4.y += prev.y; o4.z += prev.z; o4.w += prev.w;
    }
    *(float4*)op = o4;
  }
}

// ---------------------------------------------------------------------------
extern "C" void kernel_launch(void* const* d_in, const int* in_sizes, int n_in,
                              void* d_out, int out_size, void* d_ws, size_t ws_size,
                              hipStream_t stream) {
  (void)in_sizes; (void)n_in; (void)out_size; (void)ws_size;
  const float* x      = (const float*)d_in[0];
  const float* w_qkv  = (const float*)d_in[1];
  const float* w_proj = (const float*)d_in[2];
  float* out = (float*)d_out;

  float* qkv  = (float*)d_ws;                          // 27648 x 1536
  float* osum = qkv + (size_t)M_TOT * QKV_LD;          // 27648 x 512
  // ws needed: (27648*1536 + 27648*512)*4 B = 226.5 MB

  // 1) qkv = x @ w_qkv
  sgemm128<<<(M_TOT / 128) * (QKV_LD / 128), 256, 0, stream>>>(
      x, w_qkv, qkv, M_TOT, QKV_LD, Cc);

  // 2) three decomposed attentions, accumulated into osum
  //    d=0 (h,w seq; t batch):  str1=576 str2=24  strE=1
  //    d=1 (h,t seq; w batch):  str1=576 str2=1   strE=24
  //    d=2 (w,t seq; h batch):  str1=24  str2=1   strE=576
  attn_decomp<<<48 * NHEAD * NTILE, 256, 0, stream>>>(qkv, osum, 576, 24, 1, 0);
  attn_decomp<<<48 * NHEAD * NTILE, 256, 0, stream>>>(qkv, osum, 576, 1, 24, 1);
  attn_decomp<<<48 * NHEAD * NTILE, 256, 0, stream>>>(qkv, osum, 24, 1, 576, 1);

  // 3) out = osum @ w_proj
  sgemm128<<<(M_TOT / 128) * (Cc / 128), 256, 0, stream>>>(
      osum, w_proj, out, M_TOT, Cc, Cc);
}

// Round 2
// 1392.387 us; speedup vs baseline: 1.8021x; 1.8021x over previous
//
#include <hip/hip_runtime.h>
#include <math.h>

// Problem constants (fixed by setup_inputs: b=2, H=W=T=24, c=512, heads=8)
constexpr int Cc     = 512;
constexpr int NHEAD  = 8;
constexpr int HD     = 64;
constexpr int NTOK   = 13824;          // tokens per batch element (24^3)
constexpr int BATCH  = 2;
constexpr int M_TOT  = BATCH * NTOK;   // 27648 total rows
constexpr int QKV_LD = 3 * Cc;         // 1536
constexpr int SEQLEN = 576;            // 24*24 per decomposed attention
constexpr int NTILE  = SEQLEN / 64;    // 9 k-tiles of 64

typedef short s16x8 __attribute__((ext_vector_type(8)));
typedef short s16x4 __attribute__((ext_vector_type(4)));
typedef float f32x4 __attribute__((ext_vector_type(4)));

__device__ __forceinline__ unsigned short f2bf(float f) {
  unsigned u = __float_as_uint(f);
  unsigned r = u + 0x7fffu + ((u >> 16) & 1u);
  return (unsigned short)(r >> 16);
}
__device__ __forceinline__ float bf2f(unsigned short b) {
  return __uint_as_float(((unsigned)b) << 16);
}

// ---------------------------------------------------------------------------
// fp32 tiled GEMM (unchanged from round 1 — works, near fp32 roofline)
// ---------------------------------------------------------------------------
__global__ __launch_bounds__(256, 2)
void sgemm128(const float* __restrict__ A, const float* __restrict__ B,
              float* __restrict__ C, int M, int N, int K) {
  constexpr int BM = 128, BN = 128, BK = 8;
  __shared__ float As[BK][BM];
  __shared__ float Bs[BK][BN];

  const int nbx = N / BN;
  const int bx = blockIdx.x % nbx;
  const int by = blockIdx.x / nbx;
  const int tid = threadIdx.x;
  const int tx = tid & 15;
  const int ty = tid >> 4;

  float acc[8][8] = {};

  const float* Ab = A + (size_t)by * BM * K;
  const float* Bb = B + (size_t)bx * BN;

  const int ar = tid >> 1;
  const int ac = (tid & 1) << 2;
  const int br = tid >> 5;
  const int bc = (tid & 31) << 2;

  for (int k0 = 0; k0 < K; k0 += BK) {
    float4 av = *(const float4*)(Ab + (size_t)ar * K + k0 + ac);
    float4 bv = *(const float4*)(Bb + (size_t)(k0 + br) * N + bc);
    __syncthreads();
    As[ac + 0][ar] = av.x;
    As[ac + 1][ar] = av.y;
    As[ac + 2][ar] = av.z;
    As[ac + 3][ar] = av.w;
    *(float4*)&Bs[br][bc] = bv;
    __syncthreads();

#pragma unroll
    for (int kk = 0; kk < BK; ++kk) {
      float a[8], b[8];
      *(float4*)(a)     = *(const float4*)&As[kk][ty * 8];
      *(float4*)(a + 4) = *(const float4*)&As[kk][ty * 8 + 4];
      *(float4*)(b)     = *(const float4*)&Bs[kk][tx * 8];
      *(float4*)(b + 4) = *(const float4*)&Bs[kk][tx * 8 + 4];
#pragma unroll
      for (int i = 0; i < 8; ++i)
#pragma unroll
        for (int j = 0; j < 8; ++j)
          acc[i][j] = fmaf(a[i], b[j], acc[i][j]);
    }
  }

  float* Cb = C + (size_t)(by * BM + ty * 8) * N + bx * BN + tx * 8;
#pragma unroll
  for (int i = 0; i < 8; ++i) {
    float4 c0 = make_float4(acc[i][0], acc[i][1], acc[i][2], acc[i][3]);
    float4 c1 = make_float4(acc[i][4], acc[i][5], acc[i][6], acc[i][7]);
    *(float4*)(Cb + (size_t)i * N)     = c0;
    *(float4*)(Cb + (size_t)i * N + 4) = c1;
  }
}

// ---------------------------------------------------------------------------
// MFMA flash attention for one decomposition.
// Block = 256 thr = 4 waves; block handles (be, head, qt): 64 q-rows.
// Wave w owns q-strip [16w, 16w+16). K/V tiles of 64 staged to LDS as bf16.
// QK^T: 2-way split (qh+ql)(kh+kl) -> 3 MFMA terms (fp32-accurate logits).
// PV: plain bf16 (P, V), error ~1e-3 << pass threshold.
// LDS tiles 64x64 bf16, XOR swizzle on 16B chunks: conflict-free b128 frags.
// mfma_f32_16x16x32_bf16 layouts:
//   A: row=lane&15, k=8*(lane>>4)+j ; B: k=8*(lane>>4)+j, col=lane&15
//   D: col=lane&15, row=4*(lane>>4)+reg
// ---------------------------------------------------------------------------
__global__ __launch_bounds__(256, 4)
void attn_mfma(const float* __restrict__ qkv, float* __restrict__ osum,
               int str1, int str2, int strE, int accumulate) {
  __shared__ __align__(16) unsigned short KhS[4096];
  __shared__ __align__(16) unsigned short KlS[4096];
  __shared__ __align__(16) unsigned short VtS[4096];  // V transposed [d][kcol]
  __shared__ __align__(16) unsigned short PsS[4096];  // P bf16 [q][kcol]

  const int bi   = blockIdx.x;
  const int qt   = bi % NTILE;
  const int head = (bi / NTILE) & 7;
  const int be   = bi / (NTILE * NHEAD);
  const int bb   = be / 24;
  const int e    = be % 24;

  const int tid  = threadIdx.x;
  const int w    = tid >> 6;
  const int lane = tid & 63;
  const int l15  = lane & 15;
  const int lg   = lane >> 4;   // 0..3

  const size_t base_tok = (size_t)bb * NTOK + (size_t)e * strE;
  const float* qbase = qkv + base_tok * QKV_LD + head * HD;
  const float* kbase = qbase + Cc;
  const float* vbase = qbase + 2 * Cc;

  // ---- load Q fragments directly global->reg (scaled by 8), hi/lo split ----
  s16x8 qh[2], ql[2];
  {
    int s  = qt * 64 + w * 16 + l15;
    int no = (s / 24) * str1 + (s % 24) * str2;
    const float* qp = qbase + (size_t)no * QKV_LD + lg * 8;
#pragma unroll
    for (int ks = 0; ks < 2; ++ks) {
      float4 x0 = *(const float4*)(qp + ks * 32);
      float4 x1 = *(const float4*)(qp + ks * 32 + 4);
      float xs[8] = {x0.x, x0.y, x0.z, x0.w, x1.x, x1.y, x1.z, x1.w};
#pragma unroll
      for (int j = 0; j < 8; ++j) {
        float v = xs[j] * 8.0f;              // q * sqrt(hd)
        unsigned short h = f2bf(v);
        qh[ks][j] = (short)h;
        ql[ks][j] = (short)f2bf(v - bf2f(h));
      }
    }
  }

  float m_run[4], l_run[4];
  f32x4 Ov[4];
  const f32x4 fzero = {0.0f, 0.0f, 0.0f, 0.0f};
#pragma unroll
  for (int rr = 0; rr < 4; ++rr) { m_run[rr] = -1e30f; l_run[rr] = 0.0f; }
#pragma unroll
  for (int n = 0; n < 4; ++n) Ov[n] = fzero;

  for (int kt = 0; kt < NTILE; ++kt) {
    __syncthreads();  // all waves done reading previous K/V
    // ---- stage K tile (hi/lo split) ----
    {
      int r = tid & 63;
      int s = kt * 64 + r;
      const float* kp = kbase + (size_t)((s / 24) * str1 + (s % 24) * str2) * QKV_LD;
#pragma unroll
      for (int i = 0; i < 4; ++i) {
        int c = (w << 2) + i;                 // float4 chunk, d = 4c
        float4 kv = *(const float4*)(kp + c * 4);
        float kf[4] = {kv.x, kv.y, kv.z, kv.w};
        s16x4 hv, lv;
#pragma unroll
        for (int j = 0; j < 4; ++j) {
          unsigned short h = f2bf(kf[j]);
          hv[j] = (short)h;
          lv[j] = (short)f2bf(kf[j] - bf2f(h));
        }
        int woff = (r << 6) + (((c >> 1) ^ (r & 7)) << 3) + ((c & 1) << 2);
        *(s16x4*)&KhS[woff] = hv;
        *(s16x4*)&KlS[woff] = lv;
      }
    }
    // ---- stage V tile transposed: Vt[d][kcol] ----
    {
      int rp = (tid & 31) * 2;
      int cb = tid >> 5;                      // 0..7
      int s0 = kt * 64 + rp, s1 = s0 + 1;
      const float* vp0 = vbase + (size_t)((s0 / 24) * str1 + (s0 % 24) * str2) * QKV_LD;
      const float* vp1 = vbase + (size_t)((s1 / 24) * str1 + (s1 % 24) * str2) * QKV_LD;
#pragma unroll
      for (int ci = 0; ci < 2; ++ci) {
        int c = cb + ci * 8;                  // d chunk 0..15
        float4 a = *(const float4*)(vp0 + c * 4);
        float4 b = *(const float4*)(vp1 + c * 4);
        float af[4] = {a.x, a.y, a.z, a.w};
        float bf_[4] = {b.x, b.y, b.z, b.w};
#pragma unroll
        for (int j = 0; j < 4; ++j) {
          int d = c * 4 + j;
          unsigned pack = (unsigned)f2bf(af[j]) | ((unsigned)f2bf(bf_[j]) << 16);
          int off = (d << 6) + (((rp >> 3) ^ (d & 7)) << 3) + (rp & 7);
          *(unsigned*)&VtS[off] = pack;
        }
      }
    }
    __syncthreads();

    // ---- S = (Qh+Ql)(Kh+Kl)^T via 3 MFMA terms ----
    f32x4 Sv[4];
#pragma unroll
    for (int n = 0; n < 4; ++n) Sv[n] = fzero;
#pragma unroll
    for (int ks = 0; ks < 2; ++ks) {
#pragma unroll
      for (int n = 0; n < 4; ++n) {
        int krow = (n << 4) + l15;
        int off  = (krow << 6) + (((ks * 4 + lg) ^ (krow & 7)) << 3);
        s16x8 kfh = *(const s16x8*)&KhS[off];
        s16x8 kfl = *(const s16x8*)&KlS[off];
        Sv[n] = __builtin_amdgcn_mfma_f32_16x16x32_bf16(qh[ks], kfh, Sv[n], 0, 0, 0);
        Sv[n] = __builtin_amdgcn_mfma_f32_16x16x32_bf16(ql[ks], kfh, Sv[n], 0, 0, 0);
        Sv[n] = __builtin_amdgcn_mfma_f32_16x16x32_bf16(qh[ks], kfl, Sv[n], 0, 0, 0);
      }
    }

    // ---- online softmax (rows = 4*lg + rr; reduce across 16 lanes) ----
    float alpha[4];
#pragma unroll
    for (int rr = 0; rr < 4; ++rr) {
      float m0 = fmaxf(fmaxf(Sv[0][rr], Sv[1][rr]), fmaxf(Sv[2][rr], Sv[3][rr]));
      m0 = fmaxf(m0, __shfl_xor(m0, 1));
      m0 = fmaxf(m0, __shfl_xor(m0, 2));
      m0 = fmaxf(m0, __shfl_xor(m0, 4));
      m0 = fmaxf(m0, __shfl_xor(m0, 8));
      float mn = fmaxf(m_run[rr], m0);
      alpha[rr] = __expf(m_run[rr] - mn);
      m_run[rr] = mn;
    }
#pragma unroll
    for (int rr = 0; rr < 4; ++rr) {
      float ts = 0.0f;
#pragma unroll
      for (int n = 0; n < 4; ++n) {
        float p = __expf(Sv[n][rr] - m_run[rr]);
        Sv[n][rr] = p;
        ts += p;
      }
      ts += __shfl_xor(ts, 1);
      ts += __shfl_xor(ts, 2);
      ts += __shfl_xor(ts, 4);
      ts += __shfl_xor(ts, 8);
      l_run[rr] = l_run[rr] * alpha[rr] + ts;
#pragma unroll
      for (int n = 0; n < 4; ++n) Ov[n][rr] *= alpha[rr];
    }

    // ---- write P (bf16) to LDS, own-wave rows only ----
    {
      int prow_base = (w << 4) + (lg << 2);
#pragma unroll
      for (int n = 0; n < 4; ++n) {
        int col = (n << 4) + l15;
#pragma unroll
        for (int rr = 0; rr < 4; ++rr) {
          int row = prow_base + rr;
          int off = (row << 6) + (((col >> 3) ^ (row & 7)) << 3) + (col & 7);
          PsS[off] = f2bf(Sv[n][rr]);
        }
      }
    }

    // ---- O += P @ V ----
#pragma unroll
    for (int ks = 0; ks < 2; ++ks) {
      int arow = (w << 4) + l15;
      int aoff = (arow << 6) + (((ks * 4 + lg) ^ (arow & 7)) << 3);
      s16x8 pa = *(const s16x8*)&PsS[aoff];
#pragma unroll
      for (int n = 0; n < 4; ++n) {
        int vrow = (n << 4) + l15;
        int voff = (vrow << 6) + (((ks * 4 + lg) ^ (vrow & 7)) << 3);
        s16x8 vb = *(const s16x8*)&VtS[voff];
        Ov[n] = __builtin_amdgcn_mfma_f32_16x16x32_bf16(pa, vb, Ov[n], 0, 0, 0);
      }
    }
  }

  // ---- epilogue: normalize + write/accumulate ----
  float inv[4];
#pragma unroll
  for (int rr = 0; rr < 4; ++rr) inv[rr] = 1.0f / l_run[rr];
#pragma unroll
  for (int rr = 0; rr < 4; ++rr) {
    int srow = qt * 64 + (w << 4) + (lg << 2) + rr;
    int no = (srow / 24) * str1 + (srow % 24) * str2;
    float* orow = osum + (base_tok + no) * (size_t)Cc + head * HD + l15;
#pragma unroll
    for (int n = 0; n < 4; ++n) {
      float* op = orow + (n << 4);
      float v = Ov[n][rr] * inv[rr];
      if (accumulate) v += *op;
      *op = v;
    }
  }
}

// ---------------------------------------------------------------------------
extern "C" void kernel_launch(void* const* d_in, const int* in_sizes, int n_in,
                              void* d_out, int out_size, void* d_ws, size_t ws_size,
                              hipStream_t stream) {
  (void)in_sizes; (void)n_in; (void)out_size; (void)ws_size;
  const float* x      = (const float*)d_in[0];
  const float* w_qkv  = (const float*)d_in[1];
  const float* w_proj = (const float*)d_in[2];
  float* out = (float*)d_out;

  float* qkv  = (float*)d_ws;                 // 27648 x 1536
  float* osum = qkv + (size_t)M_TOT * QKV_LD; // 27648 x 512

  // 1) qkv = x @ w_qkv
  sgemm128<<<(M_TOT / 128) * (QKV_LD / 128), 256, 0, stream>>>(
      x, w_qkv, qkv, M_TOT, QKV_LD, Cc);

  // 2) three decomposed attentions, accumulated into osum
  attn_mfma<<<48 * NHEAD * NTILE, 256, 0, stream>>>(qkv, osum, 576, 24, 1, 0);
  attn_mfma<<<48 * NHEAD * NTILE, 256, 0, stream>>>(qkv, osum, 576, 1, 24, 1);
  attn_mfma<<<48 * NHEAD * NTILE, 256, 0, stream>>>(qkv, osum, 24, 1, 576, 1);

  // 3) out = osum @ w_proj
  sgemm128<<<(M_TOT / 128) * (Cc / 128), 256, 0, stream>>>(
      osum, w_proj, out, M_TOT, Cc, Cc);
}

// Round 3
// 886.856 us; speedup vs baseline: 2.8293x; 1.5700x over previous
//
#include <hip/hip_runtime.h>
#include <math.h>

// Problem constants (fixed by setup_inputs: b=2, H=W=T=24, c=512, heads=8)
constexpr int Cc     = 512;
constexpr int NHEAD  = 8;
constexpr int HD     = 64;
constexpr int NTOK   = 13824;          // tokens per batch element (24^3)
constexpr int BATCH  = 2;
constexpr int M_TOT  = BATCH * NTOK;   // 27648 total rows
constexpr int QKV_LD = 3 * Cc;         // 1536
constexpr int SEQLEN = 576;            // 24*24 per decomposed attention
constexpr int NTILE  = SEQLEN / 64;    // 9 k-tiles of 64
constexpr int KT     = 16;             // K=512 / 32 per MFMA step (all GEMMs)

typedef short s16x8 __attribute__((ext_vector_type(8)));
typedef short s16x4 __attribute__((ext_vector_type(4)));
typedef float f32x4 __attribute__((ext_vector_type(4)));

__device__ __forceinline__ unsigned short f2bf(float f) {
  unsigned u = __float_as_uint(f);
  unsigned r = u + 0x7fffu + ((u >> 16) & 1u);
  return (unsigned short)(r >> 16);
}
__device__ __forceinline__ float bf2f(unsigned short b) {
  return __uint_as_float(((unsigned)b) << 16);
}

// ---------------------------------------------------------------------------
// Convert fp32 row-major A[M][512] into fragment-major bf16 (hi, optional lo).
// Fragment (mt, kt) = 1024 B block; lane l owns A[mt*16 + (l&15)][kt*32 + 8*(l>>4) + j]
// so a wave's MFMA A-operand load is one fully-coalesced 1 KiB read.
// grid: M*64/256 blocks of 256 (exact for M=27648).
// ---------------------------------------------------------------------------
template<bool WRITE_LO>
__global__ __launch_bounds__(256)
void conv_a_frag(const float* __restrict__ src, s16x8* __restrict__ dh,
                 s16x8* __restrict__ dl) {
  int g  = blockIdx.x * 256 + threadIdx.x;   // fragment-chunk id
  int l  = g & 63;
  int t  = g >> 6;
  int kt = t & (KT - 1);
  int mt = t >> 4;
  const float* p = src + (size_t)(mt * 16 + (l & 15)) * 512 + kt * 32 + (l >> 4) * 8;
  float4 a = *(const float4*)p;
  float4 b = *(const float4*)(p + 4);
  float xs[8] = {a.x, a.y, a.z, a.w, b.x, b.y, b.z, b.w};
  s16x8 h, lo;
#pragma unroll
  for (int j = 0; j < 8; ++j) {
    unsigned short hh = f2bf(xs[j]);
    h[j] = (short)hh;
    if (WRITE_LO) lo[j] = (short)f2bf(xs[j] - bf2f(hh));
  }
  dh[g] = h;
  if (WRITE_LO) dl[g] = lo;
}

// ---------------------------------------------------------------------------
// Convert fp32 row-major B[512][N] into fragment-major bf16 (hi, optional lo).
// Fragment (nt, kt): lane l owns B[kt*32 + 8*(l>>4) + j][nt*16 + (l&15)].
// grid: KT*(N/16)*64/256 blocks.
// ---------------------------------------------------------------------------
template<bool WRITE_LO>
__global__ __launch_bounds__(256)
void conv_b_frag(const float* __restrict__ src, s16x8* __restrict__ dh,
                 s16x8* __restrict__ dl, int N) {
  int g  = blockIdx.x * 256 + threadIdx.x;
  int l  = g & 63;
  int t  = g >> 6;
  int kt = t & (KT - 1);
  int nt = t >> 4;
  int col  = nt * 16 + (l & 15);
  int row0 = kt * 32 + (l >> 4) * 8;
  s16x8 h, lo;
#pragma unroll
  for (int j = 0; j < 8; ++j) {
    float v = src[(size_t)(row0 + j) * N + col];
    unsigned short hh = f2bf(v);
    h[j] = (short)hh;
    if (WRITE_LO) lo[j] = (short)f2bf(v - bf2f(hh));
  }
  dh[g] = h;
  if (WRITE_LO) dl[g] = lo;
}

// ---------------------------------------------------------------------------
// No-LDS MFMA GEMM on fragment-major bf16 operands. C fp32 row-major.
// Block 256 thr = 4 waves (2x2), tile 128x128, each wave 64x64 (4x4 frags).
// SPLIT==3: C = Ah*Bh + Al*Bh + Ah*Bl (2-way bf16 split, ~fp32 accuracy).
// SPLIT==1: C = Ah*Bh (plain bf16).
// All operand loads are contiguous 1 KiB per wave (no LDS, no barriers).
// ---------------------------------------------------------------------------
template<int SPLIT>
__global__ __launch_bounds__(256)
void gemm_frag(const s16x8* __restrict__ Ah, const s16x8* __restrict__ Al,
               const s16x8* __restrict__ Bh, const s16x8* __restrict__ Bl,
               float* __restrict__ C, int nbx, int n0, int N_ld, int ntoff) {
  // bijective XCD swizzle (all grids are multiples of 8)
  int nwg = gridDim.x;
  int cpx = nwg >> 3;
  int bid = blockIdx.x;
  int swz = (bid & 7) * cpx + (bid >> 3);
  int bx = swz % nbx;
  int by = swz / nbx;

  int tid  = threadIdx.x;
  int lane = tid & 63;
  int w    = tid >> 6;
  int wm   = w & 1;
  int wn   = w >> 1;
  int mt0  = by * 8 + wm * 4;          // A fragment row base
  int ntG  = ntoff + bx * 8 + wn * 4;  // B fragment col base (in converted array)

  const f32x4 fz = {0.0f, 0.0f, 0.0f, 0.0f};
  f32x4 acc[4][4];
#pragma unroll
  for (int mi = 0; mi < 4; ++mi)
#pragma unroll
    for (int ni = 0; ni < 4; ++ni) acc[mi][ni] = fz;

#pragma unroll 2
  for (int kt = 0; kt < KT; ++kt) {
    s16x8 ah[4], bh[4];
#pragma unroll
    for (int mi = 0; mi < 4; ++mi)
      ah[mi] = Ah[(size_t)(((mt0 + mi) * KT + kt) * 64 + lane)];
#pragma unroll
    for (int ni = 0; ni < 4; ++ni)
      bh[ni] = Bh[(size_t)(((ntG + ni) * KT + kt) * 64 + lane)];

    if constexpr (SPLIT == 3) {
      s16x8 al[4], bl[4];
#pragma unroll
      for (int mi = 0; mi < 4; ++mi)
        al[mi] = Al[(size_t)(((mt0 + mi) * KT + kt) * 64 + lane)];
#pragma unroll
      for (int ni = 0; ni < 4; ++ni)
        bl[ni] = Bl[(size_t)(((ntG + ni) * KT + kt) * 64 + lane)];
#pragma unroll
      for (int mi = 0; mi < 4; ++mi)
#pragma unroll
        for (int ni = 0; ni < 4; ++ni) {
          acc[mi][ni] = __builtin_amdgcn_mfma_f32_16x16x32_bf16(ah[mi], bh[ni], acc[mi][ni], 0, 0, 0);
          acc[mi][ni] = __builtin_amdgcn_mfma_f32_16x16x32_bf16(al[mi], bh[ni], acc[mi][ni], 0, 0, 0);
          acc[mi][ni] = __builtin_amdgcn_mfma_f32_16x16x32_bf16(ah[mi], bl[ni], acc[mi][ni], 0, 0, 0);
        }
    } else {
#pragma unroll
      for (int mi = 0; mi < 4; ++mi)
#pragma unroll
        for (int ni = 0; ni < 4; ++ni)
          acc[mi][ni] = __builtin_amdgcn_mfma_f32_16x16x32_bf16(ah[mi], bh[ni], acc[mi][ni], 0, 0, 0);
    }
  }

  // epilogue: D layout col = lane&15, row = 4*(lane>>4) + r
  int lg = lane >> 4, l15 = lane & 15;
#pragma unroll
  for (int mi = 0; mi < 4; ++mi) {
#pragma unroll
    for (int r = 0; r < 4; ++r) {
      int row = by * 128 + wm * 64 + mi * 16 + lg * 4 + r;
      float* cp = C + (size_t)row * N_ld + n0 + bx * 128 + wn * 64 + l15;
#pragma unroll
      for (int ni = 0; ni < 4; ++ni) cp[ni * 16] = acc[mi][ni][r];
    }
  }
}

// ---------------------------------------------------------------------------
// MFMA flash attention (unchanged from round 2 — verified correct).
// ---------------------------------------------------------------------------
__global__ __launch_bounds__(256, 4)
void attn_mfma(const float* __restrict__ qkv, float* __restrict__ osum,
               int str1, int str2, int strE, int accumulate) {
  __shared__ __align__(16) unsigned short KhS[4096];
  __shared__ __align__(16) unsigned short KlS[4096];
  __shared__ __align__(16) unsigned short VtS[4096];  // V transposed [d][kcol]
  __shared__ __align__(16) unsigned short PsS[4096];  // P bf16 [q][kcol]

  const int bi   = blockIdx.x;
  const int qt   = bi % NTILE;
  const int head = (bi / NTILE) & 7;
  const int be   = bi / (NTILE * NHEAD);
  const int bb   = be / 24;
  const int e    = be % 24;

  const int tid  = threadIdx.x;
  const int w    = tid >> 6;
  const int lane = tid & 63;
  const int l15  = lane & 15;
  const int lg   = lane >> 4;   // 0..3

  const size_t base_tok = (size_t)bb * NTOK + (size_t)e * strE;
  const float* qbase = qkv + base_tok * QKV_LD + head * HD;
  const float* kbase = qbase + Cc;
  const float* vbase = qbase + 2 * Cc;

  // ---- load Q fragments global->reg (scaled by 8), hi/lo split ----
  s16x8 qh[2], ql[2];
  {
    int s  = qt * 64 + w * 16 + l15;
    int no = (s / 24) * str1 + (s % 24) * str2;
    const float* qp = qbase + (size_t)no * QKV_LD + lg * 8;
#pragma unroll
    for (int ks = 0; ks < 2; ++ks) {
      float4 x0 = *(const float4*)(qp + ks * 32);
      float4 x1 = *(const float4*)(qp + ks * 32 + 4);
      float xs[8] = {x0.x, x0.y, x0.z, x0.w, x1.x, x1.y, x1.z, x1.w};
#pragma unroll
      for (int j = 0; j < 8; ++j) {
        float v = xs[j] * 8.0f;              // q * sqrt(hd)
        unsigned short h = f2bf(v);
        qh[ks][j] = (short)h;
        ql[ks][j] = (short)f2bf(v - bf2f(h));
      }
    }
  }

  float m_run[4], l_run[4];
  f32x4 Ov[4];
  const f32x4 fzero = {0.0f, 0.0f, 0.0f, 0.0f};
#pragma unroll
  for (int rr = 0; rr < 4; ++rr) { m_run[rr] = -1e30f; l_run[rr] = 0.0f; }
#pragma unroll
  for (int n = 0; n < 4; ++n) Ov[n] = fzero;

  for (int kt = 0; kt < NTILE; ++kt) {
    __syncthreads();
    // ---- stage K tile (hi/lo split) ----
    {
      int r = tid & 63;
      int s = kt * 64 + r;
      const float* kp = kbase + (size_t)((s / 24) * str1 + (s % 24) * str2) * QKV_LD;
#pragma unroll
      for (int i = 0; i < 4; ++i) {
        int c = (w << 2) + i;
        float4 kv = *(const float4*)(kp + c * 4);
        float kf[4] = {kv.x, kv.y, kv.z, kv.w};
        s16x4 hv, lv;
#pragma unroll
        for (int j = 0; j < 4; ++j) {
          unsigned short h = f2bf(kf[j]);
          hv[j] = (short)h;
          lv[j] = (short)f2bf(kf[j] - bf2f(h));
        }
        int woff = (r << 6) + (((c >> 1) ^ (r & 7)) << 3) + ((c & 1) << 2);
        *(s16x4*)&KhS[woff] = hv;
        *(s16x4*)&KlS[woff] = lv;
      }
    }
    // ---- stage V tile transposed: Vt[d][kcol] ----
    {
      int rp = (tid & 31) * 2;
      int cb = tid >> 5;
      int s0 = kt * 64 + rp, s1 = s0 + 1;
      const float* vp0 = vbase + (size_t)((s0 / 24) * str1 + (s0 % 24) * str2) * QKV_LD;
      const float* vp1 = vbase + (size_t)((s1 / 24) * str1 + (s1 % 24) * str2) * QKV_LD;
#pragma unroll
      for (int ci = 0; ci < 2; ++ci) {
        int c = cb + ci * 8;
        float4 a = *(const float4*)(vp0 + c * 4);
        float4 b = *(const float4*)(vp1 + c * 4);
        float af[4] = {a.x, a.y, a.z, a.w};
        float bf_[4] = {b.x, b.y, b.z, b.w};
#pragma unroll
        for (int j = 0; j < 4; ++j) {
          int d = c * 4 + j;
          unsigned pack = (unsigned)f2bf(af[j]) | ((unsigned)f2bf(bf_[j]) << 16);
          int off = (d << 6) + (((rp >> 3) ^ (d & 7)) << 3) + (rp & 7);
          *(unsigned*)&VtS[off] = pack;
        }
      }
    }
    __syncthreads();

    // ---- S = (Qh+Ql)(Kh+Kl)^T via 3 MFMA terms ----
    f32x4 Sv[4];
#pragma unroll
    for (int n = 0; n < 4; ++n) Sv[n] = fzero;
#pragma unroll
    for (int ks = 0; ks < 2; ++ks) {
#pragma unroll
      for (int n = 0; n < 4; ++n) {
        int krow = (n << 4) + l15;
        int off  = (krow << 6) + (((ks * 4 + lg) ^ (krow & 7)) << 3);
        s16x8 kfh = *(const s16x8*)&KhS[off];
        s16x8 kfl = *(const s16x8*)&KlS[off];
        Sv[n] = __builtin_amdgcn_mfma_f32_16x16x32_bf16(qh[ks], kfh, Sv[n], 0, 0, 0);
        Sv[n] = __builtin_amdgcn_mfma_f32_16x16x32_bf16(ql[ks], kfh, Sv[n], 0, 0, 0);
        Sv[n] = __builtin_amdgcn_mfma_f32_16x16x32_bf16(qh[ks], kfl, Sv[n], 0, 0, 0);
      }
    }

    // ---- online softmax ----
    float alpha[4];
#pragma unroll
    for (int rr = 0; rr < 4; ++rr) {
      float m0 = fmaxf(fmaxf(Sv[0][rr], Sv[1][rr]), fmaxf(Sv[2][rr], Sv[3][rr]));
      m0 = fmaxf(m0, __shfl_xor(m0, 1));
      m0 = fmaxf(m0, __shfl_xor(m0, 2));
      m0 = fmaxf(m0, __shfl_xor(m0, 4));
      m0 = fmaxf(m0, __shfl_xor(m0, 8));
      float mn = fmaxf(m_run[rr], m0);
      alpha[rr] = __expf(m_run[rr] - mn);
      m_run[rr] = mn;
    }
#pragma unroll
    for (int rr = 0; rr < 4; ++rr) {
      float ts = 0.0f;
#pragma unroll
      for (int n = 0; n < 4; ++n) {
        float p = __expf(Sv[n][rr] - m_run[rr]);
        Sv[n][rr] = p;
        ts += p;
      }
      ts += __shfl_xor(ts, 1);
      ts += __shfl_xor(ts, 2);
      ts += __shfl_xor(ts, 4);
      ts += __shfl_xor(ts, 8);
      l_run[rr] = l_run[rr] * alpha[rr] + ts;
#pragma unroll
      for (int n = 0; n < 4; ++n) Ov[n][rr] *= alpha[rr];
    }

    // ---- write P (bf16) to LDS ----
    {
      int prow_base = (w << 4) + (lg << 2);
#pragma unroll
      for (int n = 0; n < 4; ++n) {
        int col = (n << 4) + l15;
#pragma unroll
        for (int rr = 0; rr < 4; ++rr) {
          int row = prow_base + rr;
          int off = (row << 6) + (((col >> 3) ^ (row & 7)) << 3) + (col & 7);
          PsS[off] = f2bf(Sv[n][rr]);
        }
      }
    }

    // ---- O += P @ V ----
#pragma unroll
    for (int ks = 0; ks < 2; ++ks) {
      int arow = (w << 4) + l15;
      int aoff = (arow << 6) + (((ks * 4 + lg) ^ (arow & 7)) << 3);
      s16x8 pa = *(const s16x8*)&PsS[aoff];
#pragma unroll
      for (int n = 0; n < 4; ++n) {
        int vrow = (n << 4) + l15;
        int voff = (vrow << 6) + (((ks * 4 + lg) ^ (vrow & 7)) << 3);
        s16x8 vb = *(const s16x8*)&VtS[voff];
        Ov[n] = __builtin_amdgcn_mfma_f32_16x16x32_bf16(pa, vb, Ov[n], 0, 0, 0);
      }
    }
  }

  // ---- epilogue ----
  float inv[4];
#pragma unroll
  for (int rr = 0; rr < 4; ++rr) inv[rr] = 1.0f / l_run[rr];
#pragma unroll
  for (int rr = 0; rr < 4; ++rr) {
    int srow = qt * 64 + (w << 4) + (lg << 2) + rr;
    int no = (srow / 24) * str1 + (srow % 24) * str2;
    float* orow = osum + (base_tok + no) * (size_t)Cc + head * HD + l15;
#pragma unroll
    for (int n = 0; n < 4; ++n) {
      float* op = orow + (n << 4);
      float v = Ov[n][rr] * inv[rr];
      if (accumulate) v += *op;
      *op = v;
    }
  }
}

// ---------------------------------------------------------------------------
extern "C" void kernel_launch(void* const* d_in, const int* in_sizes, int n_in,
                              void* d_out, int out_size, void* d_ws, size_t ws_size,
                              hipStream_t stream) {
  (void)in_sizes; (void)n_in; (void)out_size; (void)ws_size;
  const float* x      = (const float*)d_in[0];
  const float* w_qkv  = (const float*)d_in[1];
  const float* w_proj = (const float*)d_in[2];
  float* out = (float*)d_out;

  // ---- workspace layout (peak ~230 MB, overlays noted) ----
  char* ws = (char*)d_ws;
  constexpr size_t QKV_B  = (size_t)M_TOT * QKV_LD * 4;   // 169,869,312
  constexpr size_t AH_B   = (size_t)M_TOT * Cc * 2;       //  28,311,552
  float* qkv = (float*)ws;                                // [0, QKV_B)
  s16x8* Ah  = (s16x8*)(ws + QKV_B);                      // x hi  (frag-major)
  s16x8* Al  = (s16x8*)(ws + QKV_B + AH_B);               // x lo
  float* osum = (float*)(ws + QKV_B);                     // overlays Ah+Al (dead after qkv gemm)
  s16x8* Bh  = (s16x8*)(ws + QKV_B + 2 * AH_B);           // w_qkv hi (1.57 MB)
  s16x8* Bl  = (s16x8*)(ws + QKV_B + 2 * AH_B + 1572864); // w_qkv lo
  s16x8* Oh  = (s16x8*)ws;                                // overlays qkv (dead after attn)
  s16x8* Ph  = (s16x8*)(ws + AH_B);                       // overlays qkv tail

  // 1) operand conversion: x -> Ah/Al, w_qkv -> Bh/Bl (fragment-major)
  conv_a_frag<true><<<M_TOT * 64 / 256, 256, 0, stream>>>(x, Ah, Al);
  conv_b_frag<true><<<KT * (QKV_LD / 16) * 64 / 256, 256, 0, stream>>>(w_qkv, Bh, Bl, QKV_LD);

  // 2) qkv GEMM: q,k columns split-bf16 (3 MFMA terms), v columns plain
  gemm_frag<3><<<(M_TOT / 128) * 8, 256, 0, stream>>>(Ah, Al, Bh, Bl, qkv,
                                                      8, 0, QKV_LD, 0);
  gemm_frag<1><<<(M_TOT / 128) * 4, 256, 0, stream>>>(Ah, nullptr, Bh, nullptr, qkv,
                                                      4, 1024, QKV_LD, 64);

  // 3) three decomposed attentions, accumulated into osum
  attn_mfma<<<48 * NHEAD * NTILE, 256, 0, stream>>>(qkv, osum, 576, 24, 1, 0);
  attn_mfma<<<48 * NHEAD * NTILE, 256, 0, stream>>>(qkv, osum, 576, 1, 24, 1);
  attn_mfma<<<48 * NHEAD * NTILE, 256, 0, stream>>>(qkv, osum, 24, 1, 576, 1);

  // 4) proj GEMM (plain bf16): out = osum @ w_proj
  conv_a_frag<false><<<M_TOT * 64 / 256, 256, 0, stream>>>(osum, Oh, nullptr);
  conv_b_frag<false><<<KT * (Cc / 16) * 64 / 256, 256, 0, stream>>>(w_proj, Ph, nullptr, Cc);
  gemm_frag<1><<<(M_TOT / 128) * 4, 256, 0, stream>>>(Oh, nullptr, Ph, nullptr, out,
                                                      4, 0, Cc, 0);
}